// Round 16
// baseline (129.081 us; speedup 1.0000x reference)
//
#include <hip/hip_runtime.h>

// B=16 images, A=65536 anchors, G=32 gts. Inputs float32; output slot read as
// bf16 low-16-bits (dual-encode store gives absmax 0.0 -> keep it).
// R16 = R15 (125.3us best) + ONE change: matchforce AT 4 -> 2 (grid 1024 ->
// 2048 blocks, 8 blk/CU -> up to 8 waves/SIMD). Matchforce is latency-bound
// on dependent shfl chains (R4 counters; R15's unroll 2->4 = -1.7us confirms);
// ILP is register-capped, so raise TLP instead. R9 (AT 4->8, TLP halved)
// regressed -- this is the measured-supported inverse move.
#define BB 16
#define AA 65536
#define GG 32
#define NB 8192
#define KOFF 59904u          // __float_as_uint(2^-10) >> 14
#define AT 2                 // anchors per thread in k_matchforce
#define APB (256 * AT)       // 512 anchors per block
#define MBLK (AA / APB)      // 128 match blocks per image
#define NSEG 16              // stats segments per image
#define SEGA (AA / NSEG)     // 4096 anchors per stats block

// All scratch in device globals; every buffer fully rewritten each call
// before being read (g_done armed by k_matchforce). Re-poison safe.
__device__ unsigned char      g_mask[(size_t)BB * AA];
__device__ unsigned char      g_bidx[(size_t)BB * AA];
__device__ unsigned long long g_fpart[(size_t)BB * GG * MBLK];  // 512 KB
__device__ unsigned int       g_hpart[(size_t)BB * NSEG * (NB/2)]; // 4 MB packed
__device__ float g_spart[BB * NSEG * 2];   // pos, loc partials
__device__ int   g_npart[BB * NSEG];
__device__ float g_loc[BB], g_pos[BB], g_neg[BB];
__device__ int   g_npos[BB], g_nneg[BB];
__device__ int   g_done;                   // armed to 0 by k_matchforce

__device__ __forceinline__ float midval(int bin) {
    return __uint_as_float((((unsigned int)bin + KOFF) << 14) | 8192u);
}

// ---------------------------------------------------------------------------
// Kernel 1: fused per-anchor match + per-gt force-match partials.
// grid (MBLK=128, B), block 256, AT=2 anchors/thread (strided, coalesced).
// Divide-free scoring: r = inter/(areaA+areaG), monotone in IoU (iou=r/(1-r)),
// argmax-equivalent; iou>0.5 <=> r>1/3. rcp 1-ulp absorbed by bf16 budget
// (R2-R15 benches: absmax 0.0).
// Per-gt wave reduction: f32-max butterfly + ballot/ffs + one shfl (R13),
// 4 chains in flight (unroll 4, R15). ~45 VGPR -> 8 waves/SIMD.
__global__ void __launch_bounds__(256, 8)
k_matchforce(const float4* __restrict__ anchors,
             const float4* __restrict__ gts) {
    __shared__ float4 sg[GG];
    __shared__ unsigned long long wkey[4][GG];
    const int b = blockIdx.y;
    const int t = threadIdx.x;
    const int wave = t >> 6, lane = t & 63;
    if (blockIdx.x == 0 && b == 0 && t == 0) g_done = 0;   // arm final combine
    if (t < GG) sg[t] = gts[(size_t)b * GG + t];
    __syncthreads();

    const size_t abase = (size_t)b * AA + (size_t)blockIdx.x * APB;

    float ax0[AT], ay0[AT], ax1[AT], ay1[AT], aar[AT], best[AT];
    int bg[AT];
#pragma unroll
    for (int j = 0; j < AT; ++j) {
        const float4 av = anchors[abase + j * 256 + t];
        ax0[j] = av.x; ay0[j] = av.y; ax1[j] = av.z; ay1[j] = av.w;
        aar[j] = (av.z - av.x) * (av.w - av.y);
        best[j] = -1.0f; bg[j] = 0;
    }

#pragma unroll 4
    for (int g = 0; g < GG; ++g) {
        const float4 gb = sg[g];
        const float ga = (gb.z - gb.x) * (gb.w - gb.y);
        float fbest = -1.0f;              // r >= 0 always -> j=0 wins init
        int fo = t;                       // block-local offset of j=0 anchor
#pragma unroll
        for (int j = 0; j < AT; ++j) {
            const float lx = fmaxf(ax0[j], gb.x), ly = fmaxf(ay0[j], gb.y);
            const float rx = fminf(ax1[j], gb.z), ry = fminf(ay1[j], gb.w);
            const float w = fmaxf(rx - lx, 0.0f), h = fmaxf(ry - ly, 0.0f);
            const float inter = w * h;
            const float s = aar[j] + ga;                    // areaA + areaG > 0
            const float r = inter * __builtin_amdgcn_rcpf(s);
            if (r > best[j]) { best[j] = r; bg[j] = g; }    // strict >: first max
            if (r > fbest)   { fbest = r; fo = j * 256 + t; }
        }
        // wave reduction: value max, then first max-holding lane's offset.
        float m = fbest;
#pragma unroll
        for (int off = 1; off < 64; off <<= 1)
            m = fmaxf(m, __shfl_xor(m, off, 64));
        const unsigned long long bal = __ballot(fbest == m);
        const int first = __ffsll(bal) - 1;
        const int wfo = __shfl(fo, first, 64);   // wave-uniform broadcast
        if (lane == 0)
            wkey[wave][g] = ((unsigned long long)__float_as_uint(m) << 32) |
                            (unsigned long long)(0xFFFFFFFFu - (unsigned int)wfo);
    }

#pragma unroll
    for (int j = 0; j < AT; ++j) {
        g_mask[abase + j * 256 + t] = (best[j] > (1.0f / 3.0f)) ? 1 : 0;
        g_bidx[abase + j * 256 + t] = (unsigned char)bg[j];
    }
    __syncthreads();
    if (t < GG) {
        unsigned long long k = wkey[0][t];
#pragma unroll
        for (int w = 1; w < 4; ++w) {
            const unsigned long long k1 = wkey[w][t];
            if (k1 > k) k = k1;
        }
        const unsigned int off = 0xFFFFFFFFu - (unsigned int)(k & 0xFFFFFFFFull);
        const unsigned int ga = (unsigned int)(blockIdx.x * APB) + off;
        g_fpart[((size_t)b * GG + t) * MBLK + blockIdx.x] =
            (k & 0xFFFFFFFF00000000ull) |
            (unsigned long long)(0xFFFFFFFFu - ga);
    }
}

// ---------------------------------------------------------------------------
// Kernel 2: segmented per-image stats. grid (NSEG=16, B), block 1024.
// (R12-proven: 16 waves/CU.) fpart fold: 32 gts x 32 chunks of 4 (MBLK=128),
// 5-level shfl width 32; chunk-0 lanes mark in-segment winners in a 512 B
// bitmap. uint4 LDS-hist init + writeout. No runtime-indexed local arrays
// (R11), no global atomics (R7), no fences (R14).
__global__ void __launch_bounds__(1024)
k_stats(const float4* __restrict__ bbox,
        const float* __restrict__ conf,
        const float4* __restrict__ gts) {
    __shared__ float4 sg[GG];
    __shared__ unsigned int hp[NB / 2];       // 16 KB packed hist (u16 counts)
    __shared__ unsigned int bmap[SEGA / 32];  // 512 B forced-positive bitmap
    __shared__ float rf[1024], rf2[1024];
    __shared__ unsigned int ru[1024];
    const int b = blockIdx.y, seg = blockIdx.x, t = threadIdx.x;
    if (t < GG) sg[t] = gts[(size_t)b * GG + t];
    *(uint4*)&hp[4 * t] = make_uint4(0u, 0u, 0u, 0u);
    if (t < SEGA / 32) bmap[t] = 0u;
    __syncthreads();

    // fold force-match winners; mark ones landing in this segment
    {
        const int gg = t >> 5, p = t & 31;    // 1024 threads = 32 gts x 32
        const unsigned long long* fp =
            &g_fpart[((size_t)b * GG + gg) * MBLK + p * 4];
        unsigned long long k = fp[0];
#pragma unroll
        for (int m = 1; m < 4; ++m) {
            const unsigned long long v = fp[m];
            if (v > k) k = v;
        }
#pragma unroll
        for (int off = 1; off < 32; off <<= 1) {
            const unsigned long long o = __shfl_xor(k, off, 32);
            if (o > k) k = o;
        }
        if (p == 0) {
            const unsigned int a = 0xFFFFFFFFu - (unsigned int)(k & 0xFFFFFFFFull);
            const int la = (int)a - seg * SEGA;
            if (la >= 0 && la < SEGA) atomicOr(&bmap[la >> 5], 1u << (la & 31));
        }
    }
    __syncthreads();

    const size_t base = (size_t)b * AA + (size_t)seg * SEGA;   // anchor units
    const float4* c4 = (const float4*)(conf + base);
    const uchar4* m4 = (const uchar4*)(g_mask + base);
    const uchar4* x4 = (const uchar4*)(g_bidx + base);
    const float4* bb4 = bbox + base;

    float pos = 0.0f, loc = 0.0f;
    int np = 0;
    {
        const int idx = t;                     // 4 consecutive anchors/thread
        const float4 p4 = c4[idx];
        const uchar4 mm = m4[idx];
        const uchar4 xx = x4[idx];
        const unsigned int bw = (bmap[idx >> 3] >> ((idx & 7) * 4)) & 0xFu;
        const float pv[4] = {p4.x, p4.y, p4.z, p4.w};
        const unsigned char mv[4] = {mm.x, mm.y, mm.z, mm.w};
        const unsigned char xv[4] = {xx.x, xx.y, xx.z, xx.w};
#pragma unroll
        for (int c = 0; c < 4; ++c) {
            const float p = pv[c];
            if (mv[c] | ((bw >> c) & 1u)) {
                np += 1;
                pos += -logf(p);
                const float4 bv = bb4[4 * idx + c];
                const float4 gb = sg[xv[c]];
                const float d0 = (bv.x + bv.z) * 0.5f - (gb.x + gb.z) * 0.5f;
                const float d1 = (bv.y + bv.w) * 0.5f - (gb.y + gb.w) * 0.5f;
                const float d2 = (bv.z - bv.x) - (gb.z - gb.x);
                const float d3 = (bv.w - bv.y) - (gb.w - gb.y);
                float ds[4] = {d0, d1, d2, d3};
#pragma unroll
                for (int q = 0; q < 4; ++q) {
                    float ax = fabsf(ds[q]);
                    loc += (ax < 1.0f) ? 0.5f * ax * ax : ax - 0.5f;
                }
            } else {
                const float nb = -log1pf(-p);
                int key = (int)(__float_as_uint(nb) >> 14) - (int)KOFF;
                key = key < 0 ? 0 : (key > NB - 1 ? NB - 1 : key);
                atomicAdd(&hp[key >> 1], 1u << ((key & 1) << 4));
            }
        }
    }
    // block reduce np/pos/loc (barriers also fence the LDS hist atomics)
    ru[t] = (unsigned int)np; rf[t] = pos; rf2[t] = loc;
    __syncthreads();
    for (int w = 512; w > 0; w >>= 1) {
        if (t < w) { ru[t] += ru[t + w]; rf[t] += rf[t + w]; rf2[t] += rf2[t + w]; }
        __syncthreads();
    }
    if (t == 0) {
        g_npart[b * NSEG + seg] = (int)ru[0];
        g_spart[(b * NSEG + seg) * 2 + 0] = rf[0];
        g_spart[(b * NSEG + seg) * 2 + 1] = rf2[0];
    }
    uint4* outp = (uint4*)(g_hpart + ((size_t)b * NSEG + seg) * (NB / 2));
    outp[t] = *(const uint4*)&hp[4 * t];       // coalesced 16B/lane writeout
}

// ---------------------------------------------------------------------------
// Kernel 3: per-image fold + hard-negative top-k + (last block) final combine.
// grid B, block 1024. uint4 fold (R13).
__global__ void __launch_bounds__(1024) k_select(unsigned int* __restrict__ out) {
    __shared__ unsigned int hist[NB];         // 32 KB
    __shared__ unsigned int ru[1024];
    __shared__ unsigned int s2[32];
    __shared__ float sh_pos, sh_loc;
    __shared__ int sh_np, sh_k, sh_bsel;
    __shared__ unsigned int sh_take;
    __shared__ float rf[1024];

    const int b = blockIdx.x, t = threadIdx.x;
    // fold 16 packed partial hists -> u32 LDS hist (uint4 per thread)
    {
        unsigned int s0 = 0, s1 = 0, s2v = 0, s3 = 0,
                     s4 = 0, s5 = 0, s6 = 0, s7 = 0;
        const uint4* hbase = (const uint4*)(g_hpart + (size_t)b * NSEG * (NB / 2));
#pragma unroll
        for (int s = 0; s < NSEG; ++s) {
            const uint4 v = hbase[s * (NB / 8) + t];   // NB/2 words = NB/8 uint4
            s0 += v.x & 0xFFFFu; s1 += v.x >> 16;
            s2v += v.y & 0xFFFFu; s3 += v.y >> 16;
            s4 += v.z & 0xFFFFu; s5 += v.z >> 16;
            s6 += v.w & 0xFFFFu; s7 += v.w >> 16;
        }
        hist[8 * t + 0] = s0; hist[8 * t + 1] = s1;
        hist[8 * t + 2] = s2v; hist[8 * t + 3] = s3;
        hist[8 * t + 4] = s4; hist[8 * t + 5] = s5;
        hist[8 * t + 6] = s6; hist[8 * t + 7] = s7;
    }
    if (t < NSEG) {                            // 16-lane seg-partial fold
        int np = g_npart[b * NSEG + t];
        float pos = g_spart[(b * NSEG + t) * 2 + 0];
        float loc = g_spart[(b * NSEG + t) * 2 + 1];
#pragma unroll
        for (int off = 8; off > 0; off >>= 1) {
            np  += __shfl_xor(np,  off, 16);
            pos += __shfl_xor(pos, off, 16);
            loc += __shfl_xor(loc, off, 16);
        }
        if (t == 0) { sh_np = np; sh_pos = pos; sh_loc = loc; }
    }
    __syncthreads();
    const int np_tot = sh_np;

    // descending chunk counts: thread t covers bins NB-1-8t .. NB-8-8t
    unsigned int c = 0;
    const int hi = NB - 1 - t * 8;
#pragma unroll
    for (int j = 0; j < 8; ++j) c += hist[hi - j];
    ru[t] = c;
    __syncthreads();
    if (t < 32) {
        unsigned int x = 0;
#pragma unroll
        for (int j = 0; j < 32; ++j) x += ru[t * 32 + j];
        s2[t] = x;
    }
    __syncthreads();
    if (t == 0) {
        int k = 3 * np_tot;
        const int maxneg = AA - np_tot;
        if (k > maxneg) k = maxneg;
        sh_k = k;
        int bsel = NB;            // NB => nothing selected
        unsigned int take = 0;
        if (k > 0) {
            unsigned int cum = 0;
            int u = 0;
            while (u < 31 && cum + s2[u] < (unsigned int)k) { cum += s2[u]; ++u; }
            int cc = u * 32;
            while (cc < 1023 && cum + ru[cc] < (unsigned int)k) { cum += ru[cc]; ++cc; }
            const int h2 = NB - 1 - cc * 8;
            int j = 0;
            while (j < 7 && cum + hist[h2 - j] < (unsigned int)k) { cum += hist[h2 - j]; ++j; }
            bsel = h2 - j;
            take = (unsigned int)k - cum;
        }
        sh_bsel = bsel; sh_take = take;
    }
    __syncthreads();
    const int bsel = sh_bsel;
    float negp = 0.0f;
    for (int j = t; j < NB; j += 1024)
        if (j > bsel) { unsigned int cnt = hist[j]; if (cnt) negp += (float)cnt * midval(j); }
    rf[t] = negp;
    __syncthreads();
    for (int w = 512; w > 0; w >>= 1) {
        if (t < w) rf[t] += rf[t + w];
        __syncthreads();
    }
    if (t == 0) {
        float neg = 0.0f;
        if (sh_k > 0) neg = rf[0] + (float)sh_take * midval(bsel < NB ? bsel : 0);
        g_loc[b] = sh_loc; g_pos[b] = sh_pos; g_neg[b] = neg;
        g_npos[b] = np_tot; g_nneg[b] = sh_k;

        __threadfence();                        // publish before counting in
        const int old = atomicAdd(&g_done, 1);
        if (old == BB - 1) {                    // last image: final combine
            __threadfence();
            float loc = 0.0f, conf = 0.0f;
            int tot = 0;
            for (int bb = 0; bb < BB; ++bb) {
                const float lv = __hip_atomic_load(&g_loc[bb],  __ATOMIC_RELAXED, __HIP_MEMORY_SCOPE_AGENT);
                const float pv = __hip_atomic_load(&g_pos[bb],  __ATOMIC_RELAXED, __HIP_MEMORY_SCOPE_AGENT);
                const float nv = __hip_atomic_load(&g_neg[bb],  __ATOMIC_RELAXED, __HIP_MEMORY_SCOPE_AGENT);
                const int   np = __hip_atomic_load(&g_npos[bb], __ATOMIC_RELAXED, __HIP_MEMORY_SCOPE_AGENT);
                const int   nn = __hip_atomic_load(&g_nneg[bb], __ATOMIC_RELAXED, __HIP_MEMORY_SCOPE_AGENT);
                loc += lv;
                conf += pv / (float)(np > 1 ? np : 1) +
                        nv / (float)(nn > 1 ? nn : 1);
                tot += np;
            }
            const float total = loc / (float)(tot > 1 ? tot : 1) + conf / (float)BB;
            const unsigned int u = __float_as_uint(total);
            const unsigned int r = 0x7FFFu + ((u >> 16) & 1u);
            const unsigned int bf = (u + r) >> 16;      // bf16(total), RNE
            out[0] = (bf << 16) | bf;
        }
    }
}

extern "C" void kernel_launch(void* const* d_in, const int* in_sizes, int n_in,
                              void* d_out, int out_size, void* d_ws, size_t ws_size,
                              hipStream_t stream) {
    const float4* bbox    = (const float4*)d_in[0];
    const float*  conf    = (const float*)d_in[1];
    const float4* anchors = (const float4*)d_in[2];
    const float4* gts     = (const float4*)d_in[3];

    k_matchforce<<<dim3(MBLK, BB), 256, 0, stream>>>(anchors, gts);
    k_stats<<<dim3(NSEG, BB), 1024, 0, stream>>>(bbox, conf, gts);
    k_select<<<BB, 1024, 0, stream>>>((unsigned int*)d_out);
}

// Round 18
// 123.380 us; speedup vs baseline: 1.0462x; 1.0462x over previous
//
#include <hip/hip_runtime.h>

// B=16 images, A=65536 anchors, G=32 gts. Inputs float32; output slot read as
// bf16 low-16-bits (dual-encode store gives absmax 0.0 -> keep it).
// R18 = R15 EXACT (measured best: 125.3us; R17 bench was an infra failure,
// not a kernel verdict -- resubmitting per the R1 precedent).
// AT sweep closed (R9: AT=8 worse, R16: AT=2 worse; AT=4 optimal).
// Structure: 3-dispatch split (fusion refuted twice: R11/R14, in-kernel
// cross-block handoff ~+120us on non-coherent-XCD-L2 hardware; extra
// dispatch costs ~+9.5us: R8/R10 vs R6). Best measured configuration.
#define BB 16
#define AA 65536
#define GG 32
#define NB 8192
#define KOFF 59904u          // __float_as_uint(2^-10) >> 14
#define AT 4                 // anchors per thread in k_matchforce (optimal)
#define APB (256 * AT)       // 1024 anchors per block
#define MBLK (AA / APB)      // 64 match blocks per image
#define NSEG 16              // stats segments per image
#define SEGA (AA / NSEG)     // 4096 anchors per stats block

// All scratch in device globals; every buffer fully rewritten each call
// before being read (g_done armed by k_matchforce). Re-poison safe.
__device__ unsigned char      g_mask[(size_t)BB * AA];
__device__ unsigned char      g_bidx[(size_t)BB * AA];
__device__ unsigned long long g_fpart[(size_t)BB * GG * MBLK];  // 256 KB
__device__ unsigned int       g_hpart[(size_t)BB * NSEG * (NB/2)]; // 4 MB packed
__device__ float g_spart[BB * NSEG * 2];   // pos, loc partials
__device__ int   g_npart[BB * NSEG];
__device__ float g_loc[BB], g_pos[BB], g_neg[BB];
__device__ int   g_npos[BB], g_nneg[BB];
__device__ int   g_done;                   // armed to 0 by k_matchforce

__device__ __forceinline__ float midval(int bin) {
    return __uint_as_float((((unsigned int)bin + KOFF) << 14) | 8192u);
}

// ---------------------------------------------------------------------------
// Kernel 1: fused per-anchor match + per-gt force-match partials.
// grid (MBLK=64, B), block 256, AT=4 anchors/thread (strided, coalesced).
// Divide-free scoring: r = inter/(areaA+areaG), monotone in IoU (iou=r/(1-r)),
// argmax-equivalent; iou>0.5 <=> r>1/3. rcp 1-ulp absorbed by bf16 budget
// (R2-R16 benches: absmax 0.0).
// Per-gt wave reduction: f32-max butterfly + ballot/ffs + one shfl (R13),
// 4 independent chains in flight (unroll 4, R15: latency-bound -> ILP).
__global__ void __launch_bounds__(256, 4)
k_matchforce(const float4* __restrict__ anchors,
             const float4* __restrict__ gts) {
    __shared__ float4 sg[GG];
    __shared__ unsigned long long wkey[4][GG];
    const int b = blockIdx.y;
    const int t = threadIdx.x;
    const int wave = t >> 6, lane = t & 63;
    if (blockIdx.x == 0 && b == 0 && t == 0) g_done = 0;   // arm final combine
    if (t < GG) sg[t] = gts[(size_t)b * GG + t];
    __syncthreads();

    const size_t abase = (size_t)b * AA + (size_t)blockIdx.x * APB;

    float ax0[AT], ay0[AT], ax1[AT], ay1[AT], aar[AT], best[AT];
    int bg[AT];
#pragma unroll
    for (int j = 0; j < AT; ++j) {
        const float4 av = anchors[abase + j * 256 + t];
        ax0[j] = av.x; ay0[j] = av.y; ax1[j] = av.z; ay1[j] = av.w;
        aar[j] = (av.z - av.x) * (av.w - av.y);
        best[j] = -1.0f; bg[j] = 0;
    }

#pragma unroll 4
    for (int g = 0; g < GG; ++g) {
        const float4 gb = sg[g];
        const float ga = (gb.z - gb.x) * (gb.w - gb.y);
        float fbest = -1.0f;              // r >= 0 always -> j=0 wins init
        int fo = t;                       // block-local offset of j=0 anchor
#pragma unroll
        for (int j = 0; j < AT; ++j) {
            const float lx = fmaxf(ax0[j], gb.x), ly = fmaxf(ay0[j], gb.y);
            const float rx = fminf(ax1[j], gb.z), ry = fminf(ay1[j], gb.w);
            const float w = fmaxf(rx - lx, 0.0f), h = fmaxf(ry - ly, 0.0f);
            const float inter = w * h;
            const float s = aar[j] + ga;                    // areaA + areaG > 0
            const float r = inter * __builtin_amdgcn_rcpf(s);
            if (r > best[j]) { best[j] = r; bg[j] = g; }    // strict >: first max
            if (r > fbest)   { fbest = r; fo = j * 256 + t; }
        }
        // wave reduction: value max, then first max-holding lane's offset.
        float m = fbest;
#pragma unroll
        for (int off = 1; off < 64; off <<= 1)
            m = fmaxf(m, __shfl_xor(m, off, 64));
        const unsigned long long bal = __ballot(fbest == m);
        const int first = __ffsll(bal) - 1;
        const int wfo = __shfl(fo, first, 64);   // wave-uniform broadcast
        if (lane == 0)
            wkey[wave][g] = ((unsigned long long)__float_as_uint(m) << 32) |
                            (unsigned long long)(0xFFFFFFFFu - (unsigned int)wfo);
    }

#pragma unroll
    for (int j = 0; j < AT; ++j) {
        g_mask[abase + j * 256 + t] = (best[j] > (1.0f / 3.0f)) ? 1 : 0;
        g_bidx[abase + j * 256 + t] = (unsigned char)bg[j];
    }
    __syncthreads();
    if (t < GG) {
        unsigned long long k = wkey[0][t];
#pragma unroll
        for (int w = 1; w < 4; ++w) {
            const unsigned long long k1 = wkey[w][t];
            if (k1 > k) k = k1;
        }
        const unsigned int off = 0xFFFFFFFFu - (unsigned int)(k & 0xFFFFFFFFull);
        const unsigned int ga = (unsigned int)(blockIdx.x * APB) + off;
        g_fpart[((size_t)b * GG + t) * MBLK + blockIdx.x] =
            (k & 0xFFFFFFFF00000000ull) |
            (unsigned long long)(0xFFFFFFFFu - ga);
    }
}

// ---------------------------------------------------------------------------
// Kernel 2: segmented per-image stats. grid (NSEG=16, B), block 1024.
// (R12-proven: 16 waves/CU.) fpart fold: 32 gts x 32 chunks of 2, 5-level
// shfl width 32; chunk-0 lanes mark in-segment winners in a 512 B bitmap.
// uint4 LDS-hist init + writeout. No runtime-indexed local arrays (R11),
// no global atomics (R7), no fences (R14).
__global__ void __launch_bounds__(1024)
k_stats(const float4* __restrict__ bbox,
        const float* __restrict__ conf,
        const float4* __restrict__ gts) {
    __shared__ float4 sg[GG];
    __shared__ unsigned int hp[NB / 2];       // 16 KB packed hist (u16 counts)
    __shared__ unsigned int bmap[SEGA / 32];  // 512 B forced-positive bitmap
    __shared__ float rf[1024], rf2[1024];
    __shared__ unsigned int ru[1024];
    const int b = blockIdx.y, seg = blockIdx.x, t = threadIdx.x;
    if (t < GG) sg[t] = gts[(size_t)b * GG + t];
    *(uint4*)&hp[4 * t] = make_uint4(0u, 0u, 0u, 0u);
    if (t < SEGA / 32) bmap[t] = 0u;
    __syncthreads();

    // fold force-match winners; mark ones landing in this segment
    {
        const int gg = t >> 5, p = t & 31;    // 1024 threads = 32 gts x 32
        const unsigned long long* fp =
            &g_fpart[((size_t)b * GG + gg) * MBLK + p * 2];
        unsigned long long k = fp[0];
        { const unsigned long long v = fp[1]; if (v > k) k = v; }
#pragma unroll
        for (int off = 1; off < 32; off <<= 1) {
            const unsigned long long o = __shfl_xor(k, off, 32);
            if (o > k) k = o;
        }
        if (p == 0) {
            const unsigned int a = 0xFFFFFFFFu - (unsigned int)(k & 0xFFFFFFFFull);
            const int la = (int)a - seg * SEGA;
            if (la >= 0 && la < SEGA) atomicOr(&bmap[la >> 5], 1u << (la & 31));
        }
    }
    __syncthreads();

    const size_t base = (size_t)b * AA + (size_t)seg * SEGA;   // anchor units
    const float4* c4 = (const float4*)(conf + base);
    const uchar4* m4 = (const uchar4*)(g_mask + base);
    const uchar4* x4 = (const uchar4*)(g_bidx + base);
    const float4* bb4 = bbox + base;

    float pos = 0.0f, loc = 0.0f;
    int np = 0;
    {
        const int idx = t;                     // 4 consecutive anchors/thread
        const float4 p4 = c4[idx];
        const uchar4 mm = m4[idx];
        const uchar4 xx = x4[idx];
        const unsigned int bw = (bmap[idx >> 3] >> ((idx & 7) * 4)) & 0xFu;
        const float pv[4] = {p4.x, p4.y, p4.z, p4.w};
        const unsigned char mv[4] = {mm.x, mm.y, mm.z, mm.w};
        const unsigned char xv[4] = {xx.x, xx.y, xx.z, xx.w};
#pragma unroll
        for (int c = 0; c < 4; ++c) {
            const float p = pv[c];
            if (mv[c] | ((bw >> c) & 1u)) {
                np += 1;
                pos += -logf(p);
                const float4 bv = bb4[4 * idx + c];
                const float4 gb = sg[xv[c]];
                const float d0 = (bv.x + bv.z) * 0.5f - (gb.x + gb.z) * 0.5f;
                const float d1 = (bv.y + bv.w) * 0.5f - (gb.y + gb.w) * 0.5f;
                const float d2 = (bv.z - bv.x) - (gb.z - gb.x);
                const float d3 = (bv.w - bv.y) - (gb.w - gb.y);
                float ds[4] = {d0, d1, d2, d3};
#pragma unroll
                for (int q = 0; q < 4; ++q) {
                    float ax = fabsf(ds[q]);
                    loc += (ax < 1.0f) ? 0.5f * ax * ax : ax - 0.5f;
                }
            } else {
                const float nb = -log1pf(-p);
                int key = (int)(__float_as_uint(nb) >> 14) - (int)KOFF;
                key = key < 0 ? 0 : (key > NB - 1 ? NB - 1 : key);
                atomicAdd(&hp[key >> 1], 1u << ((key & 1) << 4));
            }
        }
    }
    // block reduce np/pos/loc (barriers also fence the LDS hist atomics)
    ru[t] = (unsigned int)np; rf[t] = pos; rf2[t] = loc;
    __syncthreads();
    for (int w = 512; w > 0; w >>= 1) {
        if (t < w) { ru[t] += ru[t + w]; rf[t] += rf[t + w]; rf2[t] += rf2[t + w]; }
        __syncthreads();
    }
    if (t == 0) {
        g_npart[b * NSEG + seg] = (int)ru[0];
        g_spart[(b * NSEG + seg) * 2 + 0] = rf[0];
        g_spart[(b * NSEG + seg) * 2 + 1] = rf2[0];
    }
    uint4* outp = (uint4*)(g_hpart + ((size_t)b * NSEG + seg) * (NB / 2));
    outp[t] = *(const uint4*)&hp[4 * t];       // coalesced 16B/lane writeout
}

// ---------------------------------------------------------------------------
// Kernel 3: per-image fold + hard-negative top-k + (last block) final combine.
// grid B, block 1024. uint4 fold (R13).
__global__ void __launch_bounds__(1024) k_select(unsigned int* __restrict__ out) {
    __shared__ unsigned int hist[NB];         // 32 KB
    __shared__ unsigned int ru[1024];
    __shared__ unsigned int s2[32];
    __shared__ float sh_pos, sh_loc;
    __shared__ int sh_np, sh_k, sh_bsel;
    __shared__ unsigned int sh_take;
    __shared__ float rf[1024];

    const int b = blockIdx.x, t = threadIdx.x;
    // fold 16 packed partial hists -> u32 LDS hist (uint4 per thread)
    {
        unsigned int s0 = 0, s1 = 0, s2v = 0, s3 = 0,
                     s4 = 0, s5 = 0, s6 = 0, s7 = 0;
        const uint4* hbase = (const uint4*)(g_hpart + (size_t)b * NSEG * (NB / 2));
#pragma unroll
        for (int s = 0; s < NSEG; ++s) {
            const uint4 v = hbase[s * (NB / 8) + t];   // NB/2 words = NB/8 uint4
            s0 += v.x & 0xFFFFu; s1 += v.x >> 16;
            s2v += v.y & 0xFFFFu; s3 += v.y >> 16;
            s4 += v.z & 0xFFFFu; s5 += v.z >> 16;
            s6 += v.w & 0xFFFFu; s7 += v.w >> 16;
        }
        hist[8 * t + 0] = s0; hist[8 * t + 1] = s1;
        hist[8 * t + 2] = s2v; hist[8 * t + 3] = s3;
        hist[8 * t + 4] = s4; hist[8 * t + 5] = s5;
        hist[8 * t + 6] = s6; hist[8 * t + 7] = s7;
    }
    if (t < NSEG) {                            // 16-lane seg-partial fold
        int np = g_npart[b * NSEG + t];
        float pos = g_spart[(b * NSEG + t) * 2 + 0];
        float loc = g_spart[(b * NSEG + t) * 2 + 1];
#pragma unroll
        for (int off = 8; off > 0; off >>= 1) {
            np  += __shfl_xor(np,  off, 16);
            pos += __shfl_xor(pos, off, 16);
            loc += __shfl_xor(loc, off, 16);
        }
        if (t == 0) { sh_np = np; sh_pos = pos; sh_loc = loc; }
    }
    __syncthreads();
    const int np_tot = sh_np;

    // descending chunk counts: thread t covers bins NB-1-8t .. NB-8-8t
    unsigned int c = 0;
    const int hi = NB - 1 - t * 8;
#pragma unroll
    for (int j = 0; j < 8; ++j) c += hist[hi - j];
    ru[t] = c;
    __syncthreads();
    if (t < 32) {
        unsigned int x = 0;
#pragma unroll
        for (int j = 0; j < 32; ++j) x += ru[t * 32 + j];
        s2[t] = x;
    }
    __syncthreads();
    if (t == 0) {
        int k = 3 * np_tot;
        const int maxneg = AA - np_tot;
        if (k > maxneg) k = maxneg;
        sh_k = k;
        int bsel = NB;            // NB => nothing selected
        unsigned int take = 0;
        if (k > 0) {
            unsigned int cum = 0;
            int u = 0;
            while (u < 31 && cum + s2[u] < (unsigned int)k) { cum += s2[u]; ++u; }
            int cc = u * 32;
            while (cc < 1023 && cum + ru[cc] < (unsigned int)k) { cum += ru[cc]; ++cc; }
            const int h2 = NB - 1 - cc * 8;
            int j = 0;
            while (j < 7 && cum + hist[h2 - j] < (unsigned int)k) { cum += hist[h2 - j]; ++j; }
            bsel = h2 - j;
            take = (unsigned int)k - cum;
        }
        sh_bsel = bsel; sh_take = take;
    }
    __syncthreads();
    const int bsel = sh_bsel;
    float negp = 0.0f;
    for (int j = t; j < NB; j += 1024)
        if (j > bsel) { unsigned int cnt = hist[j]; if (cnt) negp += (float)cnt * midval(j); }
    rf[t] = negp;
    __syncthreads();
    for (int w = 512; w > 0; w >>= 1) {
        if (t < w) rf[t] += rf[t + w];
        __syncthreads();
    }
    if (t == 0) {
        float neg = 0.0f;
        if (sh_k > 0) neg = rf[0] + (float)sh_take * midval(bsel < NB ? bsel : 0);
        g_loc[b] = sh_loc; g_pos[b] = sh_pos; g_neg[b] = neg;
        g_npos[b] = np_tot; g_nneg[b] = sh_k;

        __threadfence();                        // publish before counting in
        const int old = atomicAdd(&g_done, 1);
        if (old == BB - 1) {                    // last image: final combine
            __threadfence();
            float loc = 0.0f, conf = 0.0f;
            int tot = 0;
            for (int bb = 0; bb < BB; ++bb) {
                const float lv = __hip_atomic_load(&g_loc[bb],  __ATOMIC_RELAXED, __HIP_MEMORY_SCOPE_AGENT);
                const float pv = __hip_atomic_load(&g_pos[bb],  __ATOMIC_RELAXED, __HIP_MEMORY_SCOPE_AGENT);
                const float nv = __hip_atomic_load(&g_neg[bb],  __ATOMIC_RELAXED, __HIP_MEMORY_SCOPE_AGENT);
                const int   np = __hip_atomic_load(&g_npos[bb], __ATOMIC_RELAXED, __HIP_MEMORY_SCOPE_AGENT);
                const int   nn = __hip_atomic_load(&g_nneg[bb], __ATOMIC_RELAXED, __HIP_MEMORY_SCOPE_AGENT);
                loc += lv;
                conf += pv / (float)(np > 1 ? np : 1) +
                        nv / (float)(nn > 1 ? nn : 1);
                tot += np;
            }
            const float total = loc / (float)(tot > 1 ? tot : 1) + conf / (float)BB;
            const unsigned int u = __float_as_uint(total);
            const unsigned int r = 0x7FFFu + ((u >> 16) & 1u);
            const unsigned int bf = (u + r) >> 16;      // bf16(total), RNE
            out[0] = (bf << 16) | bf;
        }
    }
}

extern "C" void kernel_launch(void* const* d_in, const int* in_sizes, int n_in,
                              void* d_out, int out_size, void* d_ws, size_t ws_size,
                              hipStream_t stream) {
    const float4* bbox    = (const float4*)d_in[0];
    const float*  conf    = (const float*)d_in[1];
    const float4* anchors = (const float4*)d_in[2];
    const float4* gts     = (const float4*)d_in[3];

    k_matchforce<<<dim3(MBLK, BB), 256, 0, stream>>>(anchors, gts);
    k_stats<<<dim3(NSEG, BB), 1024, 0, stream>>>(bbox, conf, gts);
    k_select<<<BB, 1024, 0, stream>>>((unsigned int*)d_out);
}